// Round 5
// baseline (170.010 us; speedup 1.0000x reference)
//
#include <hip/hip_runtime.h>
#include <hip/hip_bf16.h>

#define NB   4
#define CCH  256
#define CQK  32
#define NTOK 4096
#define LOG2E 1.4426950408889634f

typedef unsigned short u16;
typedef unsigned int   u32;
typedef __attribute__((ext_vector_type(8))) __bf16 bf16x8;
typedef __attribute__((ext_vector_type(4))) float  f32x4;

union bfu { bf16x8 v; u16 s[8]; };

static __device__ __forceinline__ u16 f2bf(float f) {
  union { __hip_bfloat16 h; u16 u; } c; c.h = __float2bfloat16(f); return c.u;
}
static __device__ __forceinline__ float bf2f(u16 u) {
  union { __hip_bfloat16 h; u16 u; } c; c.u = u; return __bfloat162float(c.h);
}
static __device__ __forceinline__ u32 f2bf2(float a, float b) {
  union { __hip_bfloat162 h; u32 u; } cv;
  cv.h = __float22bfloat162_rn(make_float2(a, b));
  return cv.u;
}
static __device__ __forceinline__ f32x4 mfma16(bf16x8 a, bf16x8 b, f32x4 c) {
  return __builtin_amdgcn_mfma_f32_16x16x32_bf16(a, b, c, 0, 0, 0);
}
static __device__ __forceinline__ f32x4 max4(f32x4 a, f32x4 b) {
  f32x4 r;
  r[0] = fmaxf(a[0], b[0]); r[1] = fmaxf(a[1], b[1]);
  r[2] = fmaxf(a[2], b[2]); r[3] = fmaxf(a[3], b[3]);
  return r;
}

// ---------------- Kernel 0: split W to bf16 hi/lo (once, tiny) ----------------
__global__ __launch_bounds__(256) void convert_w(
    const float* __restrict__ wq, const float* __restrict__ wk,
    const float* __restrict__ wv, u16* __restrict__ whi, u16* __restrict__ wlo)
{
  int i   = blockIdx.x * 256 + threadIdx.x;  // float4 index, 320*64 total
  int row = i >> 6;
  int col = (i & 63) * 4;
  const float* src = (row < 32) ? wq + row * CCH
                   : (row < 64) ? wk + (row - 32) * CCH
                                : wv + (row - 64) * CCH;
  float sc = (row < 32) ? LOG2E : 1.0f;
  float4 v = *(const float4*)(src + col);
  float f[4] = { v.x * sc, v.y * sc, v.z * sc, v.w * sc };
  u16 h[4], l[4];
#pragma unroll
  for (int j = 0; j < 4; j++) {
    h[j] = f2bf(f[j]);
    l[j] = f2bf(f[j] - bf2f(h[j]));
  }
  uint2 ph = { (u32)h[0] | ((u32)h[1] << 16), (u32)h[2] | ((u32)h[3] << 16) };
  uint2 pl = { (u32)l[0] | ((u32)l[1] << 16), (u32)l[2] | ((u32)l[3] << 16) };
  *(uint2*)(whi + (size_t)i * 4) = ph;
  *(uint2*)(wlo + (size_t)i * 4) = pl;
}

// ---------------- Kernel 1: MFMA QKV projection (n-tile 16) ----------------
__global__ __launch_bounds__(256, 3) void qkv_proj(
    const float* __restrict__ x,
    const float* __restrict__ bq, const float* __restrict__ bk,
    const float* __restrict__ bv,
    const u16* __restrict__ whi, const u16* __restrict__ wlo,
    u16* __restrict__ Qo, u16* __restrict__ Ko, u16* __restrict__ Vo)
{
  const int nt = blockIdx.x;   // 0..255
  const int b  = blockIdx.y;
  const int n0 = nt * 16;
  const int tid = threadIdx.x;
  const int w = tid >> 6, lane = tid & 63, lo = lane & 15, hi = lane >> 4;

  const f32x4 fz = { 0.f, 0.f, 0.f, 0.f };
  f32x4 acc[5];
#pragma unroll
  for (int t = 0; t < 5; t++) acc[t] = fz;

  const float* xb = x + (size_t)b * CCH * NTOK;

  for (int k = 0; k < 8; k++) {
    const int ck = k * 32;
    const float* xc = xb + (size_t)(ck + hi * 8) * NTOK + n0 + lo;
    bfu H, L;
#pragma unroll
    for (int j = 0; j < 8; j++) {
      float f  = xc[(size_t)j * NTOK];
      u16  hh  = f2bf(f);
      H.s[j] = hh;
      L.s[j] = f2bf(f - bf2f(hh));
    }
    bf16x8 xh = H.v, xl = L.v;
#pragma unroll
    for (int t = 0; t < 5; t++) {
      const int ot = w + t * 4;
      const size_t woff = (size_t)(ot * 16 + lo) * CCH + ck + hi * 8;
      bf16x8 wh = *(const bf16x8*)(whi + woff);
      bf16x8 wl = *(const bf16x8*)(wlo + woff);
      if (t == 0) {   // Q/K: D[row=o][col=n]
        acc[t] = mfma16(wh, xh, acc[t]);
        acc[t] = mfma16(wh, xl, acc[t]);
        acc[t] = mfma16(wl, xh, acc[t]);
      } else {        // V: D[row=n][col=c]
        acc[t] = mfma16(xh, wh, acc[t]);
        acc[t] = mfma16(xl, wh, acc[t]);
        acc[t] = mfma16(xh, wl, acc[t]);
      }
    }
  }

  {
    const float* bsrc = (w < 2) ? bq : bk;
    const float  sc   = (w < 2) ? LOG2E : 1.0f;
    float4 b4 = *(const float4*)(bsrc + (w & 1) * 16 + hi * 4);
    float b0 = b4.x * sc, b1 = b4.y * sc, b2 = b4.z * sc, b3 = b4.w * sc;
    u16* base = (w < 2) ? Qo : Ko;
    int n = n0 + lo;
    f32x4 a = acc[0];
    uint2 pk = { f2bf2(a[0] + b0, a[1] + b1), f2bf2(a[2] + b2, a[3] + b3) };
    *(uint2*)(base + ((size_t)b * NTOK + n) * CQK + (w & 1) * 16 + hi * 4) = pk;
  }
#pragma unroll
  for (int t = 1; t < 5; t++) {
    int c = (w + t * 4 - 4) * 16 + lo;
    float bvc = bv[c];
    f32x4 a = acc[t];
    uint2 pk = { f2bf2(a[0] + bvc, a[1] + bvc), f2bf2(a[2] + bvc, a[3] + bvc) };
    *(uint2*)(Vo + ((size_t)b * CCH + c) * NTOK + n0 + hi * 4) = pk;
  }
}

// ---------------- Kernel 2: two-pass fixed-m flash attention ----------------
// Block: 512 thr / 8 waves / 64 queries; grid 256 (1 block/CU).
// Pass A: per-wave max (q-tile w&3, m-half w>>2) via QK MFMA — no LDS/barriers.
// Pass B: fixed-m softmax (no rescale, no alpha, chunks independent). Wave role
// = (c-slice 64 = w&3, m-half 32 = w>>2): produces P(16q x 32m), consumes
// P(64q x its 32m) from XOR-swizzled LDS for PV over its 64 channels.
// Partner waves (w, w+4) hold the two m-half partial O's; combined via LDS.
__global__ __launch_bounds__(512) void attn(
    const float* __restrict__ x,
    const u16* __restrict__ Qm, const u16* __restrict__ Km,
    const u16* __restrict__ Vm, float* __restrict__ out)
{
  const int g   = blockIdx.x;
  const int lw3 = g & 7;
  const int b   = lw3 >> 1;                      // batch -> XCD pair
  const int qtb = ((g >> 3) << 1) | (lw3 & 1);
  const int q0  = qtb * 64;

  const int tid  = threadIdx.x;
  const int w    = tid >> 6;
  const int lane = tid & 63;
  const int lo   = lane & 15;
  const int hi   = lane >> 4;
  const int qt   = w & 3;        // production q-tile AND consumption c-slice
  const int mh   = w >> 2;       // m-half (both roles)
  const int qt16 = qt * 16;
  const int swz  = (lo & 3) << 2;

  __shared__ __align__(16) u32 P_lds[2][2][64][16];  // [buf][mh][n][m-word^swz]
  __shared__ float m_lds[2][64];
  __shared__ float l_lds[2][64];
  __shared__ f32x4 acc_x[4][8][64];                  // epilogue exchange (32KB)

  const f32x4 fz = { 0.f, 0.f, 0.f, 0.f };
  const u16* Kb = Km + (size_t)b * NTOK * CQK;
  const u16* Vb = Vm + (size_t)b * CCH * NTOK;

  // Q fragment (B-operand): col n = q0+qt16+lo, k = d = 8hi+j.
  bf16x8 qf = *(const bf16x8*)(Qm + ((size_t)b * NTOK + q0 + qt16 + lo) * CQK + hi * 8);

  // ---- Pass A: max over (16q x 2048m), per-lane then 2 shuffles. ----
  f32x4 cm4 = { -INFINITY, -INFINITY, -INFINITY, -INFINITY };
  const size_t mbase = (size_t)mh * 2048;
#pragma unroll 2
  for (int it = 0; it < 32; ++it) {
    const size_t m0 = mbase + (size_t)it * 64;
    bf16x8 k0 = *(const bf16x8*)(Kb + (m0 +  0 + lo) * CQK + hi * 8);
    bf16x8 k1 = *(const bf16x8*)(Kb + (m0 + 16 + lo) * CQK + hi * 8);
    bf16x8 k2 = *(const bf16x8*)(Kb + (m0 + 32 + lo) * CQK + hi * 8);
    bf16x8 k3 = *(const bf16x8*)(Kb + (m0 + 48 + lo) * CQK + hi * 8);
    f32x4 s0 = mfma16(k0, qf, fz);
    f32x4 s1 = mfma16(k1, qf, fz);
    f32x4 s2 = mfma16(k2, qf, fz);
    f32x4 s3 = mfma16(k3, qf, fz);
    cm4 = max4(cm4, max4(max4(s0, s1), max4(s2, s3)));
  }
  float cm = fmaxf(fmaxf(cm4[0], cm4[1]), fmaxf(cm4[2], cm4[3]));
  cm = fmaxf(cm, __shfl_xor(cm, 16));
  cm = fmaxf(cm, __shfl_xor(cm, 32));
  if (hi == 0) m_lds[mh][qt16 + lo] = cm;
  __syncthreads();
  const float mreg = fmaxf(m_lds[0][qt16 + lo], m_lds[1][qt16 + lo]);

  // ---- Pass B ----
  f32x4 acc[4][4];
#pragma unroll
  for (int t = 0; t < 4; t++)
#pragma unroll
    for (int ct = 0; ct < 4; ct++) acc[t][ct] = fz;
  float l_run = 0.f;

  bf16x8 kf0, kf1;
  auto ldk = [&](int ch) {
    const size_t m0 = (size_t)ch * 64 + mh * 32;
    kf0 = *(const bf16x8*)(Kb + (m0 +  0 + lo) * CQK + hi * 8);
    kf1 = *(const bf16x8*)(Kb + (m0 + 16 + lo) * CQK + hi * 8);
  };
  // P for chunk in (kf0,kf1) -> buffer nb. P = exp2(s - m_fixed), no rescale.
  auto produce = [&](int nb) {
    f32x4 s0 = mfma16(kf0, qf, fz);
    f32x4 s1 = mfma16(kf1, qf, fz);
    float p0 = __builtin_amdgcn_exp2f(s0[0] - mreg);
    float p1 = __builtin_amdgcn_exp2f(s0[1] - mreg);
    float p2 = __builtin_amdgcn_exp2f(s0[2] - mreg);
    float p3 = __builtin_amdgcn_exp2f(s0[3] - mreg);
    float p4 = __builtin_amdgcn_exp2f(s1[0] - mreg);
    float p5 = __builtin_amdgcn_exp2f(s1[1] - mreg);
    float p6 = __builtin_amdgcn_exp2f(s1[2] - mreg);
    float p7 = __builtin_amdgcn_exp2f(s1[3] - mreg);
    l_run += ((p0 + p1) + (p2 + p3)) + ((p4 + p5) + (p6 + p7));
    u32 c00 = f2bf2(p0, p1), c01 = f2bf2(p2, p3);
    u32 c10 = f2bf2(p4, p5), c11 = f2bf2(p6, p7);
    u32* prow = &P_lds[nb][mh][qt16 + lo][0];
    *(uint2*)(prow + (( 0 + 2 * hi) ^ swz)) = make_uint2(c00, c01);
    *(uint2*)(prow + (( 8 + 2 * hi) ^ swz)) = make_uint2(c10, c11);
  };

  ldk(0);
  produce(0);
  asm volatile("s_waitcnt lgkmcnt(0)" ::: "memory");
  __builtin_amdgcn_s_barrier();

  const int c0 = qt * 64;   // consumption channel slice
  for (int ch = 0; ch < 64; ++ch) {
    const int buf = ch & 1;
    if (ch + 1 < 64) ldk(ch + 1);

    bf16x8 vf[4];
#pragma unroll
    for (int ct = 0; ct < 4; ct++)
      vf[ct] = *(const bf16x8*)(Vb + (size_t)(c0 + ct * 16 + lo) * NTOK
                                + (size_t)ch * 64 + mh * 32 + hi * 8);
    bf16x8 af[4];
#pragma unroll
    for (int t = 0; t < 4; t++)
      af[t] = *(const bf16x8*)(&P_lds[buf][mh][t * 16 + lo][(4 * hi) ^ swz]);

    if (ch + 1 < 64) produce(buf ^ 1);

#pragma unroll
    for (int t = 0; t < 4; t++)
#pragma unroll
      for (int ct = 0; ct < 4; ct++)
        acc[t][ct] = mfma16(af[t], vf[ct], acc[t][ct]);

    asm volatile("s_waitcnt lgkmcnt(0)" ::: "memory");
    __builtin_amdgcn_s_barrier();
  }

  // ---- l reduce + epilogue (partner m-half combine, 2 phases) ----
  l_run += __shfl_xor(l_run, 16);
  l_run += __shfl_xor(l_run, 32);
  if (hi == 0) l_lds[mh][qt16 + lo] = l_run;

  const float* xb = x   + (size_t)b * CCH * NTOK;
  float*       ob = out + (size_t)b * CCH * NTOK;

#pragma unroll
  for (int ph = 0; ph < 2; ++ph) {
    if (w >= 4) {
#pragma unroll
      for (int t2 = 0; t2 < 2; t2++)
#pragma unroll
        for (int ct = 0; ct < 4; ct++)
          acc_x[qt][t2 * 4 + ct][lane] = acc[ph * 2 + t2][ct];
    }
    __syncthreads();
    if (w < 4) {
#pragma unroll
      for (int t2 = 0; t2 < 2; t2++) {
        const int t = ph * 2 + t2;
        f32x4 l0 = *(const f32x4*)&l_lds[0][t * 16 + hi * 4];
        f32x4 l1 = *(const f32x4*)&l_lds[1][t * 16 + hi * 4];
        f32x4 il;
        il[0] = 1.f / (l0[0] + l1[0]);
        il[1] = 1.f / (l0[1] + l1[1]);
        il[2] = 1.f / (l0[2] + l1[2]);
        il[3] = 1.f / (l0[3] + l1[3]);
#pragma unroll
        for (int ct = 0; ct < 4; ct++) {
          f32x4 tot = acc[t][ct] + acc_x[qt][t2 * 4 + ct][lane];
          int c = c0 + ct * 16 + lo;
          size_t base = (size_t)c * NTOK + q0 + t * 16 + hi * 4;
          float4 xr = *(const float4*)(xb + base);
          float4 o;
          o.x = tot[0] * il[0] + xr.x;
          o.y = tot[1] * il[1] + xr.y;
          o.z = tot[2] * il[2] + xr.z;
          o.w = tot[3] * il[3] + xr.w;
          *(float4*)(ob + base) = o;
        }
      }
    }
    __syncthreads();
  }
}

extern "C" void kernel_launch(void* const* d_in, const int* in_sizes, int n_in,
                              void* d_out, int out_size, void* d_ws, size_t ws_size,
                              hipStream_t stream) {
  const float* x  = (const float*)d_in[0];
  const float* wq = (const float*)d_in[1];
  const float* bq = (const float*)d_in[2];
  const float* wk = (const float*)d_in[3];
  const float* bk = (const float*)d_in[4];
  const float* wv = (const float*)d_in[5];
  const float* bv = (const float*)d_in[6];
  float* out = (float*)d_out;

  // ws (bf16): Q [4,4096,32] | K [4,4096,32] | V [4,256,4096] | Whi,Wlo [320,256]
  u16* Qp  = (u16*)d_ws;
  u16* Kp  = Qp + (size_t)NB * NTOK * CQK;
  u16* Vp  = Kp + (size_t)NB * NTOK * CQK;
  u16* Whi = Vp + (size_t)NB * CCH * NTOK;
  u16* Wlo = Whi + (size_t)320 * CCH;

  convert_w<<<80, 256, 0, stream>>>(wq, wk, wv, Whi, Wlo);
  dim3 pg(256, NB);
  qkv_proj<<<pg, 256, 0, stream>>>(x, bq, bk, bv, Whi, Wlo, Qp, Kp, Vp);
  attn<<<256, 512, 0, stream>>>(x, Qp, Kp, Vp, out);
}